// Round 5
// baseline (265.719 us; speedup 1.0000x reference)
//
#include <hip/hip_runtime.h>

typedef unsigned short u16;
typedef unsigned int   u32;

typedef float  f32x4  __attribute__((ext_vector_type(4)));
typedef __bf16 bf16x8 __attribute__((ext_vector_type(8)));

#define S_LEN  4096
#define DMODEL 1024
#define NSUB   4
#define DSUB   256
#define HFF    512
#define NTOK   16384   // B*S = 4*4096

static_assert(sizeof(bf16x8) == 16, "frag size");

__device__ __forceinline__ u16 f2bf(float f) {
    union { float f; u32 u; } v; v.f = f;
    u32 r = (v.u + 0x7fffu + ((v.u >> 16) & 1u)) >> 16;   // RNE
    return (u16)r;
}

#define MFMA16(a, b, c) __builtin_amdgcn_mfma_f32_16x16x32_bf16((a), (b), (c), 0, 0, 0)

// -------------------------------------------- fragment-packed weight repack
// dst[b][C/16][K/32][lane 64][8] = bf16(src[b][k][c]),
//   k = kt*32 + (lane>>4)*8 + j, c = ct*16 + (lane&15)
// LDS-transpose version: coalesced reads + coalesced packed writes.
// Each block: one [32k x 64c] tile -> 4 ctiles x 1 ktile of frags.
// Grid 1280: [0,256) Wg, [256,512) Wu, [512,768) Wd, [768,1280) Wo.
__global__ __launch_bounds__(256) void k_repack_all(const float* __restrict__ Wg,
                                                    const float* __restrict__ Wu,
                                                    const float* __restrict__ Wd,
                                                    const float* __restrict__ Wo,
                                                    u16* __restrict__ wgP,
                                                    u16* __restrict__ wuP,
                                                    u16* __restrict__ wdP,
                                                    u16* __restrict__ woP) {
    __shared__ float tl[32][65];
    int bid = blockIdx.x;
    const float* src; u16* dst; int K, C, rel;
    if (bid < 256)      { src = Wg; dst = wgP; K = 256;  C = 512;  rel = bid; }
    else if (bid < 512) { src = Wu; dst = wuP; K = 256;  C = 512;  rel = bid - 256; }
    else if (bid < 768) { src = Wd; dst = wdP; K = 512;  C = 256;  rel = bid - 512; }
    else                { src = Wo; dst = woP; K = 1024; C = 1024; rel = bid - 768; }
    int ncb = C >> 6, nkt = K >> 5;
    int cb = rel % ncb; int r2 = rel / ncb;
    int kt = r2 % nkt;  int b  = r2 / nkt;

    int tid = threadIdx.x;
    // coalesced read: [32 rows k][64 cols c] fp32
    {
        int r = tid >> 3, c0 = (tid & 7) * 8;
        const float* s = src + ((size_t)(b * K + kt * 32 + r)) * C + cb * 64 + c0;
        float4 v0 = *(const float4*)(s);
        float4 v1 = *(const float4*)(s + 4);
        tl[r][c0 + 0] = v0.x; tl[r][c0 + 1] = v0.y; tl[r][c0 + 2] = v0.z; tl[r][c0 + 3] = v0.w;
        tl[r][c0 + 4] = v1.x; tl[r][c0 + 5] = v1.y; tl[r][c0 + 6] = v1.z; tl[r][c0 + 7] = v1.w;
    }
    __syncthreads();
    // packed write: frag f = tid>>6 (ctile cb*4+f), lane l = tid&63
    {
        int f = tid >> 6, l = tid & 63;
        union { u16 v[8]; uint4 q; } u;
#pragma unroll
        for (int j = 0; j < 8; ++j)
            u.v[j] = f2bf(tl[(l >> 4) * 8 + j][f * 16 + (l & 15)]);
        size_t ctile = (size_t)(b * (C >> 4) + cb * 4 + f);
        *(uint4*)(dst + (ctile * nkt + kt) * 512 + l * 8) = u.q;
    }
}

// ------------------------- fused RMSNorm + RoPE (inline trig) -> bf16 h
__global__ __launch_bounds__(256) void k_norm_rope(const float* __restrict__ x,
                                                   const float* __restrict__ nw,
                                                   u16* __restrict__ h) {
    int tok = blockIdx.x;
    int s = tok & (S_LEN - 1);
    int t = threadIdx.x;
    const float* xr = x + (size_t)tok * DMODEL;
    float x0 = xr[t], x1 = xr[t + 256], x2 = xr[t + 512], x3 = xr[t + 768];
    float ss = x0 * x0 + x1 * x1 + x2 * x2 + x3 * x3;
#pragma unroll
    for (int o = 32; o > 0; o >>= 1) ss += __shfl_down(ss, o, 64);
    __shared__ float red[4];
    if ((t & 63) == 0) red[t >> 6] = ss;
    __syncthreads();
    float tot = red[0] + red[1] + red[2] + red[3];
    float sc = rsqrtf(tot * (1.0f / DMODEL) + 1e-6f);
    float n0 = x0 * sc * nw[t];
    float n1 = x1 * sc * nw[t + 256];
    float n2 = x2 * sc * nw[t + 512];
    float n3 = x3 * sc * nw[t + 768];
    // inv_freq = 10000^(-i/512) = exp(C*i), C = -ln(10000)/512
    const float C = -0.017988946039015984f;
    float sf = (float)s;
    float ang0 = sf * expf(C * (float)t);
    float ang1 = sf * expf(C * (float)(t + 256));
    float sn0, cs0, sn1, cs1;
    sincosf(ang0, &sn0, &cs0);
    sincosf(ang1, &sn1, &cs1);
    u16* hr = h + (size_t)tok * DMODEL;
    hr[t]       = f2bf(n0 * cs0 - n2 * sn0);
    hr[t + 256] = f2bf(n1 * cs1 - n3 * sn1);
    hr[t + 512] = f2bf(n2 * cs0 + n0 * sn0);
    hr[t + 768] = f2bf(n3 * cs1 + n1 * sn1);
}

// ---------------------------------------------------------- grouped SwiGLU
// grid: 128 m-blocks x 4 subspaces; 512 thr = 8 waves (2 wr x 4 wc).
// BM=128. Software-pipelined: down(hc-1) MFMAs interleave with gu(hc) MFMAs
// in the same barrier window (independent acc chains -> scheduler overlap).
// One barrier per chunk; sT double-buffered.
__global__ __launch_bounds__(512, 2) void k_swiglu(const u16* __restrict__ h,
                                                   const u16* __restrict__ wgP,   // [4][32][8][64][8]
                                                   const u16* __restrict__ wuP,   // [4][32][8][64][8]
                                                   const u16* __restrict__ wdP,   // [4][16][16][64][8]
                                                   u16* __restrict__ dmid) {
    int bid = blockIdx.x;
    int mb = bid & 127, n = bid >> 7;
    int m0 = mb * 128;
    int tid = threadIdx.x;
    int lane = tid & 63, wid = tid >> 6;
    int wr = wid >> 2, wc = wid & 3;

    __shared__ u16 sA[128 * 256];        // 64KB, swizzled
    __shared__ u16 sT[2][128 * 128];     // 2 x 32KB, swizzled

    // ---- stage h tile [128][256] (subspace n slice), swizzled
    const u16* hbase = h + (size_t)m0 * DMODEL + n * DSUB;
#pragma unroll
    for (int it = 0; it < 8; ++it) {
        int e = (tid + it * 512) * 8;
        int r = e >> 8, c = e & 255;
        uint4 v = *(const uint4*)(hbase + (size_t)r * DMODEL + c);
        u32 off = ((u32)(r * 512 + c * 2)) ^ ((u32)(r & 7) << 4);
        *(uint4*)((char*)sA + off) = v;
    }

    const f32x4 zero = {0.f, 0.f, 0.f, 0.f};
    f32x4 accd[4][4];
#pragma unroll
    for (int a = 0; a < 4; ++a)
#pragma unroll
        for (int b = 0; b < 4; ++b) accd[a][b] = zero;

    const u16* wg = wgP + (size_t)n * (32 * 8 * 512);
    const u16* wu = wuP + (size_t)n * (32 * 8 * 512);
    const u16* wd = wdP + (size_t)n * (16 * 16 * 512);

    __syncthreads();

#pragma unroll
    for (int hc = 0; hc < 4; ++hc) {
        // ======== down(hc-1) from sT[(hc-1)&1] — interleaves with gu(hc)
        if (hc > 0) {
            const u16* sTp = (const u16*)sT[(hc - 1) & 1];
#pragma unroll
            for (int k2 = 0; k2 < 4; ++k2) {
                bf16x8 afr2[4];
#pragma unroll
                for (int rt = 0; rt < 4; ++rt) {
                    int arow = wr * 64 + rt * 16 + (lane & 15);
                    int k0 = k2 * 32 + (lane >> 4) * 8;
                    u32 off = ((u32)(arow * 256 + k0 * 2)) ^ ((u32)(arow & 7) << 4);
                    afr2[rt] = *(const bf16x8*)((const char*)sTp + off);
                }
#pragma unroll
                for (int ct = 0; ct < 4; ++ct) {
                    size_t ctile = (size_t)(wc * 4 + ct);
                    size_t ktile = (size_t)((hc - 1) * 4 + k2);
                    bf16x8 bd = *(const bf16x8*)(wd + (ctile * 16 + ktile) * 512 + lane * 8);
#pragma unroll
                    for (int rt = 0; rt < 4; ++rt)
                        accd[rt][ct] = MFMA16(afr2[rt], bd, accd[rt][ct]);
                }
            }
        }

        // ======== gate/up for chunk [128 x 128]
        f32x4 accg[4][2], accu[4][2];
#pragma unroll
        for (int a = 0; a < 4; ++a)
#pragma unroll
            for (int b = 0; b < 2; ++b) { accg[a][b] = zero; accu[a][b] = zero; }

#pragma unroll
        for (int ks = 0; ks < 8; ++ks) {
            bf16x8 afr[4];
#pragma unroll
            for (int rt = 0; rt < 4; ++rt) {
                int arow = wr * 64 + rt * 16 + (lane & 15);
                int k0 = ks * 32 + (lane >> 4) * 8;
                u32 off = ((u32)(arow * 512 + k0 * 2)) ^ ((u32)(arow & 7) << 4);
                afr[rt] = *(const bf16x8*)((const char*)sA + off);
            }
#pragma unroll
            for (int ct = 0; ct < 2; ++ct) {
                size_t ctile = (size_t)(hc * 8 + wc * 2 + ct);
                bf16x8 bg = *(const bf16x8*)(wg + (ctile * 8 + ks) * 512 + lane * 8);
                bf16x8 bu = *(const bf16x8*)(wu + (ctile * 8 + ks) * 512 + lane * 8);
#pragma unroll
                for (int rt = 0; rt < 4; ++rt) {
                    accg[rt][ct] = MFMA16(afr[rt], bg, accg[rt][ct]);
                    accu[rt][ct] = MFMA16(afr[rt], bu, accu[rt][ct]);
                }
            }
        }

        // ======== t = silu(gate)*up -> sT[hc&1] (swizzled scatter)
        u16* sTc = (u16*)sT[hc & 1];
#pragma unroll
        for (int rt = 0; rt < 4; ++rt)
#pragma unroll
            for (int ct = 0; ct < 2; ++ct) {
                int rbase = wr * 64 + rt * 16 + (lane >> 4) * 4;
                int col = (wc * 2 + ct) * 16 + (lane & 15);
#pragma unroll
                for (int q = 0; q < 4; ++q) {
                    float g = accg[rt][ct][q], u = accu[rt][ct][q];
                    float tv = (g / (1.0f + __expf(-g))) * u;
                    int row = rbase + q;
                    u32 off = ((u32)(row * 256 + col * 2)) ^ ((u32)(row & 7) << 4);
                    *(u16*)((char*)sTc + off) = f2bf(tv);
                }
            }

        __syncthreads();
    }

    // ======== epilogue: down(3) from sT[1]
    {
        const u16* sTp = (const u16*)sT[1];
#pragma unroll
        for (int k2 = 0; k2 < 4; ++k2) {
            bf16x8 afr2[4];
#pragma unroll
            for (int rt = 0; rt < 4; ++rt) {
                int arow = wr * 64 + rt * 16 + (lane & 15);
                int k0 = k2 * 32 + (lane >> 4) * 8;
                u32 off = ((u32)(arow * 256 + k0 * 2)) ^ ((u32)(arow & 7) << 4);
                afr2[rt] = *(const bf16x8*)((const char*)sTp + off);
            }
#pragma unroll
            for (int ct = 0; ct < 4; ++ct) {
                size_t ctile = (size_t)(wc * 4 + ct);
                size_t ktile = (size_t)(12 + k2);
                bf16x8 bd = *(const bf16x8*)(wd + (ctile * 16 + ktile) * 512 + lane * 8);
#pragma unroll
                for (int rt = 0; rt < 4; ++rt)
                    accd[rt][ct] = MFMA16(afr2[rt], bd, accd[rt][ct]);
            }
        }
    }

    // ---- write dmid [128][256] n-slice as bf16
#pragma unroll
    for (int rt = 0; rt < 4; ++rt)
#pragma unroll
        for (int ct = 0; ct < 4; ++ct) {
            int rbase = m0 + wr * 64 + rt * 16 + (lane >> 4) * 4;
            int col = n * DSUB + wc * 64 + ct * 16 + (lane & 15);
#pragma unroll
            for (int q = 0; q < 4; ++q)
                dmid[(size_t)(rbase + q) * DMODEL + col] = f2bf(accd[rt][ct][q]);
        }
}

// -------------------------------------------------- final GEMM + residual
// grid: 128 m-blocks x 8 n-blocks; BM=128, BN=128; 512 thr = 8 waves (2x4).
// K-chunks of 128 double-buffered in 64KB LDS -> 2 blocks/CU. Split reg
// staging (issue chunk kc+2 during compute of kc).
__global__ __launch_bounds__(512, 4) void k_final(const u16* __restrict__ dmid,
                                                  const u16* __restrict__ woP,   // [64][32][64][8]
                                                  const float* __restrict__ x,
                                                  float* __restrict__ out) {
    int bid = blockIdx.x;
    int mb = bid & 127, nb = bid >> 7;
    int m0 = mb * 128, n0 = nb * 128;
    int tid = threadIdx.x;
    int lane = tid & 63, wid = tid >> 6;
    int wr = wid >> 2, wc = wid & 3;

    __shared__ u16 sA[2][128 * 128];     // 2 x 32KB, swizzled

    const f32x4 zero = {0.f, 0.f, 0.f, 0.f};
    f32x4 acc[4][2];
#pragma unroll
    for (int a = 0; a < 4; ++a)
#pragma unroll
        for (int b = 0; b < 2; ++b) acc[a][b] = zero;

    const u16* dbase = dmid + (size_t)m0 * DMODEL;

    uint4 st[2][4];                      // chunk j lives in st[j&1]
    // load chunk 0 -> st[0]; flush to sA[0]; issue chunk 1 -> st[1]
#pragma unroll
    for (int it = 0; it < 4; ++it) {
        int e = (tid + it * 512) * 8;
        int r = e >> 7, c = e & 127;
        st[0][it] = *(const uint4*)(dbase + (size_t)r * DMODEL + c);
    }
#pragma unroll
    for (int it = 0; it < 4; ++it) {
        int e = (tid + it * 512) * 8;
        int r = e >> 7, c = e & 127;
        u32 off = ((u32)(r * 256 + c * 2)) ^ ((u32)(r & 7) << 4);
        *(uint4*)((char*)sA[0] + off) = st[0][it];
    }
#pragma unroll
    for (int it = 0; it < 4; ++it) {
        int e = (tid + it * 512) * 8;
        int r = e >> 7, c = e & 127;
        st[1][it] = *(const uint4*)(dbase + (size_t)r * DMODEL + 128 + c);
    }

#pragma unroll
    for (int kc = 0; kc < 8; ++kc) {
        __syncthreads();                 // sA[kc&1] ready; sA[(kc+1)&1] free
        if (kc < 7) {                    // flush chunk kc+1 regs -> LDS
#pragma unroll
            for (int it = 0; it < 4; ++it) {
                int e = (tid + it * 512) * 8;
                int r = e >> 7, c = e & 127;
                u32 off = ((u32)(r * 256 + c * 2)) ^ ((u32)(r & 7) << 4);
                *(uint4*)((char*)sA[(kc + 1) & 1] + off) = st[(kc + 1) & 1][it];
            }
        }
        if (kc < 6) {                    // issue chunk kc+2 -> st[kc&1]
#pragma unroll
            for (int it = 0; it < 4; ++it) {
                int e = (tid + it * 512) * 8;
                int r = e >> 7, c = e & 127;
                st[kc & 1][it] = *(const uint4*)(dbase + (size_t)r * DMODEL + (kc + 2) * 128 + c);
            }
        }

        const u16* sAc = (const u16*)sA[kc & 1];
#pragma unroll
        for (int ks = 0; ks < 4; ++ks) {
            bf16x8 afr[4];
#pragma unroll
            for (int rt = 0; rt < 4; ++rt) {
                int arow = wr * 64 + rt * 16 + (lane & 15);
                int k0 = ks * 32 + (lane >> 4) * 8;
                u32 off = ((u32)(arow * 256 + k0 * 2)) ^ ((u32)(arow & 7) << 4);
                afr[rt] = *(const bf16x8*)((const char*)sAc + off);
            }
#pragma unroll
            for (int ct = 0; ct < 2; ++ct) {
                size_t ctile = (size_t)(nb * 8 + wc * 2 + ct);
                size_t ktile = (size_t)(kc * 4 + ks);
                bf16x8 wf = *(const bf16x8*)(woP + (ctile * 32 + ktile) * 512 + lane * 8);
#pragma unroll
                for (int rt = 0; rt < 4; ++rt)
                    acc[rt][ct] = MFMA16(afr[rt], wf, acc[rt][ct]);
            }
        }
    }

    // epilogue: residual add, fp32 store
#pragma unroll
    for (int rt = 0; rt < 4; ++rt)
#pragma unroll
        for (int ct = 0; ct < 2; ++ct) {
            int rbase = m0 + wr * 64 + rt * 16 + (lane >> 4) * 4;
            int col = n0 + wc * 32 + ct * 16 + (lane & 15);
#pragma unroll
            for (int q = 0; q < 4; ++q) {
                size_t o = (size_t)(rbase + q) * DMODEL + col;
                out[o] = acc[rt][ct][q] + x[o];
            }
        }
}

// ---------------------------------------------------------------- launcher
extern "C" void kernel_launch(void* const* d_in, const int* in_sizes, int n_in,
                              void* d_out, int out_size, void* d_ws, size_t ws_size,
                              hipStream_t stream) {
    const float* x  = (const float*)d_in[0];
    const float* nw = (const float*)d_in[1];
    const float* Wg = (const float*)d_in[2];
    const float* Wu = (const float*)d_in[3];
    const float* Wd = (const float*)d_in[4];
    const float* Wo = (const float*)d_in[5];
    float* out = (float*)d_out;

    char* ws = (char*)d_ws;
    const size_t MB = 1u << 20;
    u16* h    = (u16*)(ws);             // 32 MB
    u16* wgP  = (u16*)(ws + 32 * MB);   //  1 MB
    u16* wuP  = (u16*)(ws + 33 * MB);   //  1 MB
    u16* wdP  = (u16*)(ws + 34 * MB);   //  1 MB
    u16* woP  = (u16*)(ws + 35 * MB);   //  2 MB
    u16* dmid = (u16*)(ws + 37 * MB);   // 32 MB  (end: 69 MB)

    k_repack_all<<<1280, 256, 0, stream>>>(Wg, Wu, Wd, Wo, wgP, wuP, wdP, woP);
    k_norm_rope<<<NTOK, 256, 0, stream>>>(x, nw, h);
    k_swiglu<<<128 * NSUB, 512, 0, stream>>>(h, wgP, wuP, wdP, dmid);
    k_final<<<128 * 8, 512, 0, stream>>>(dmid, woP, x, out);
}

// Round 6
// 242.566 us; speedup vs baseline: 1.0954x; 1.0954x over previous
//
#include <hip/hip_runtime.h>

typedef unsigned short u16;
typedef unsigned int   u32;

typedef float  f32x4  __attribute__((ext_vector_type(4)));
typedef __bf16 bf16x8 __attribute__((ext_vector_type(8)));

#define S_LEN  4096
#define DMODEL 1024
#define NSUB   4
#define DSUB   256
#define HFF    512
#define NTOK   16384   // B*S = 4*4096

static_assert(sizeof(bf16x8) == 16, "frag size");

__device__ __forceinline__ u16 f2bf(float f) {
    union { float f; u32 u; } v; v.f = f;
    u32 r = (v.u + 0x7fffu + ((v.u >> 16) & 1u)) >> 16;   // RNE
    return (u16)r;
}

#define MFMA16(a, b, c) __builtin_amdgcn_mfma_f32_16x16x32_bf16((a), (b), (c), 0, 0, 0)

// -------------------------------------------- fragment-packed weight repack
// dst[b][C/16][K/32][lane 64][8] = bf16(src[b][k][c]),
//   k = kt*32 + (lane>>4)*8 + j, c = ct*16 + (lane&15)
// LDS-transpose: coalesced reads + coalesced packed writes.
__global__ __launch_bounds__(256) void k_repack_all(const float* __restrict__ Wg,
                                                    const float* __restrict__ Wu,
                                                    const float* __restrict__ Wd,
                                                    const float* __restrict__ Wo,
                                                    u16* __restrict__ wgP,
                                                    u16* __restrict__ wuP,
                                                    u16* __restrict__ wdP,
                                                    u16* __restrict__ woP) {
    __shared__ float tl[32][65];
    int bid = blockIdx.x;
    const float* src; u16* dst; int K, C, rel;
    if (bid < 256)      { src = Wg; dst = wgP; K = 256;  C = 512;  rel = bid; }
    else if (bid < 512) { src = Wu; dst = wuP; K = 256;  C = 512;  rel = bid - 256; }
    else if (bid < 768) { src = Wd; dst = wdP; K = 512;  C = 256;  rel = bid - 512; }
    else                { src = Wo; dst = woP; K = 1024; C = 1024; rel = bid - 768; }
    int ncb = C >> 6, nkt = K >> 5;
    int cb = rel % ncb; int r2 = rel / ncb;
    int kt = r2 % nkt;  int b  = r2 / nkt;

    int tid = threadIdx.x;
    {
        int r = tid >> 3, c0 = (tid & 7) * 8;
        const float* s = src + ((size_t)(b * K + kt * 32 + r)) * C + cb * 64 + c0;
        float4 v0 = *(const float4*)(s);
        float4 v1 = *(const float4*)(s + 4);
        tl[r][c0 + 0] = v0.x; tl[r][c0 + 1] = v0.y; tl[r][c0 + 2] = v0.z; tl[r][c0 + 3] = v0.w;
        tl[r][c0 + 4] = v1.x; tl[r][c0 + 5] = v1.y; tl[r][c0 + 6] = v1.z; tl[r][c0 + 7] = v1.w;
    }
    __syncthreads();
    {
        int f = tid >> 6, l = tid & 63;
        union { u16 v[8]; uint4 q; } u;
#pragma unroll
        for (int j = 0; j < 8; ++j)
            u.v[j] = f2bf(tl[(l >> 4) * 8 + j][f * 16 + (l & 15)]);
        size_t ctile = (size_t)(b * (C >> 4) + cb * 4 + f);
        *(uint4*)(dst + (ctile * nkt + kt) * 512 + l * 8) = u.q;
    }
}

// ------------------------- fused RMSNorm + RoPE (inline trig) -> bf16 h
__global__ __launch_bounds__(256) void k_norm_rope(const float* __restrict__ x,
                                                   const float* __restrict__ nw,
                                                   u16* __restrict__ h) {
    int tok = blockIdx.x;
    int s = tok & (S_LEN - 1);
    int t = threadIdx.x;
    const float* xr = x + (size_t)tok * DMODEL;
    float x0 = xr[t], x1 = xr[t + 256], x2 = xr[t + 512], x3 = xr[t + 768];
    float ss = x0 * x0 + x1 * x1 + x2 * x2 + x3 * x3;
#pragma unroll
    for (int o = 32; o > 0; o >>= 1) ss += __shfl_down(ss, o, 64);
    __shared__ float red[4];
    if ((t & 63) == 0) red[t >> 6] = ss;
    __syncthreads();
    float tot = red[0] + red[1] + red[2] + red[3];
    float sc = rsqrtf(tot * (1.0f / DMODEL) + 1e-6f);
    float n0 = x0 * sc * nw[t];
    float n1 = x1 * sc * nw[t + 256];
    float n2 = x2 * sc * nw[t + 512];
    float n3 = x3 * sc * nw[t + 768];
    const float C = -0.017988946039015984f;   // -ln(10000)/512
    float sf = (float)s;
    float ang0 = sf * expf(C * (float)t);
    float ang1 = sf * expf(C * (float)(t + 256));
    float sn0, cs0, sn1, cs1;
    sincosf(ang0, &sn0, &cs0);
    sincosf(ang1, &sn1, &cs1);
    u16* hr = h + (size_t)tok * DMODEL;
    hr[t]       = f2bf(n0 * cs0 - n2 * sn0);
    hr[t + 256] = f2bf(n1 * cs1 - n3 * sn1);
    hr[t + 512] = f2bf(n2 * cs0 + n0 * sn0);
    hr[t + 768] = f2bf(n3 * cs1 + n1 * sn1);
}

// ---------------------------------------------------------- grouped SwiGLU
// grid: 256 m-blocks x 4 subspaces; 512 thr = 8 waves (2 wr x 4 wc).
// BM=64 -> 64KB LDS -> 2 blocks/CU (4 waves/SIMD). Pipelined: down(hc-1)
// interleaves with gu(hc); one barrier per chunk; sT double-buffered.
__global__ __launch_bounds__(512, 2) void k_swiglu(const u16* __restrict__ h,
                                                   const u16* __restrict__ wgP,   // [4][32][8][64][8]
                                                   const u16* __restrict__ wuP,   // [4][32][8][64][8]
                                                   const u16* __restrict__ wdP,   // [4][16][16][64][8]
                                                   u16* __restrict__ dmid) {
    int bid = blockIdx.x;
    int mb = bid & 255, n = bid >> 8;
    int m0 = mb * 64;
    int tid = threadIdx.x;
    int lane = tid & 63, wid = tid >> 6;
    int wr = wid >> 2, wc = wid & 3;

    __shared__ u16 sA[64 * 256];        // 32KB, swizzled
    __shared__ u16 sT[2][64 * 128];     // 2 x 16KB, swizzled

    // ---- stage h tile [64][256] (subspace n slice), swizzled
    const u16* hbase = h + (size_t)m0 * DMODEL + n * DSUB;
#pragma unroll
    for (int it = 0; it < 4; ++it) {
        int e = (tid + it * 512) * 8;
        int r = e >> 8, c = e & 255;
        uint4 v = *(const uint4*)(hbase + (size_t)r * DMODEL + c);
        u32 off = ((u32)(r * 512 + c * 2)) ^ ((u32)(r & 7) << 4);
        *(uint4*)((char*)sA + off) = v;
    }

    const f32x4 zero = {0.f, 0.f, 0.f, 0.f};
    f32x4 accd[2][4];
#pragma unroll
    for (int a = 0; a < 2; ++a)
#pragma unroll
        for (int b = 0; b < 4; ++b) accd[a][b] = zero;

    const u16* wg = wgP + (size_t)n * (32 * 8 * 512);
    const u16* wu = wuP + (size_t)n * (32 * 8 * 512);
    const u16* wd = wdP + (size_t)n * (16 * 16 * 512);

    __syncthreads();

#pragma unroll
    for (int hc = 0; hc < 4; ++hc) {
        // ======== down(hc-1) from sT[(hc-1)&1] — interleaves with gu(hc)
        if (hc > 0) {
            const u16* sTp = (const u16*)sT[(hc - 1) & 1];
#pragma unroll
            for (int k2 = 0; k2 < 4; ++k2) {
                bf16x8 afr2[2];
#pragma unroll
                for (int rt = 0; rt < 2; ++rt) {
                    int arow = wr * 32 + rt * 16 + (lane & 15);
                    int k0 = k2 * 32 + (lane >> 4) * 8;
                    u32 off = ((u32)(arow * 256 + k0 * 2)) ^ ((u32)(arow & 7) << 4);
                    afr2[rt] = *(const bf16x8*)((const char*)sTp + off);
                }
#pragma unroll
                for (int ct = 0; ct < 4; ++ct) {
                    size_t ctile = (size_t)(wc * 4 + ct);
                    size_t ktile = (size_t)((hc - 1) * 4 + k2);
                    bf16x8 bd = *(const bf16x8*)(wd + (ctile * 16 + ktile) * 512 + lane * 8);
#pragma unroll
                    for (int rt = 0; rt < 2; ++rt)
                        accd[rt][ct] = MFMA16(afr2[rt], bd, accd[rt][ct]);
                }
            }
        }

        // ======== gate/up for chunk [64 x 128]
        f32x4 accg[2][2], accu[2][2];
#pragma unroll
        for (int a = 0; a < 2; ++a)
#pragma unroll
            for (int b = 0; b < 2; ++b) { accg[a][b] = zero; accu[a][b] = zero; }

#pragma unroll
        for (int ks = 0; ks < 8; ++ks) {
            bf16x8 afr[2];
#pragma unroll
            for (int rt = 0; rt < 2; ++rt) {
                int arow = wr * 32 + rt * 16 + (lane & 15);
                int k0 = ks * 32 + (lane >> 4) * 8;
                u32 off = ((u32)(arow * 512 + k0 * 2)) ^ ((u32)(arow & 7) << 4);
                afr[rt] = *(const bf16x8*)((const char*)sA + off);
            }
#pragma unroll
            for (int ct = 0; ct < 2; ++ct) {
                size_t ctile = (size_t)(hc * 8 + wc * 2 + ct);
                bf16x8 bg = *(const bf16x8*)(wg + (ctile * 8 + ks) * 512 + lane * 8);
                bf16x8 bu = *(const bf16x8*)(wu + (ctile * 8 + ks) * 512 + lane * 8);
#pragma unroll
                for (int rt = 0; rt < 2; ++rt) {
                    accg[rt][ct] = MFMA16(afr[rt], bg, accg[rt][ct]);
                    accu[rt][ct] = MFMA16(afr[rt], bu, accu[rt][ct]);
                }
            }
        }

        // ======== t = silu(gate)*up -> sT[hc&1] (swizzled scatter)
        u16* sTc = (u16*)sT[hc & 1];
#pragma unroll
        for (int rt = 0; rt < 2; ++rt)
#pragma unroll
            for (int ct = 0; ct < 2; ++ct) {
                int rbase = wr * 32 + rt * 16 + (lane >> 4) * 4;
                int col = (wc * 2 + ct) * 16 + (lane & 15);
#pragma unroll
                for (int q = 0; q < 4; ++q) {
                    float g = accg[rt][ct][q], u = accu[rt][ct][q];
                    float tv = (g / (1.0f + __expf(-g))) * u;
                    int row = rbase + q;
                    u32 off = ((u32)(row * 256 + col * 2)) ^ ((u32)(row & 7) << 4);
                    *(u16*)((char*)sTc + off) = f2bf(tv);
                }
            }

        __syncthreads();
    }

    // ======== epilogue: down(3) from sT[1]
    {
        const u16* sTp = (const u16*)sT[1];
#pragma unroll
        for (int k2 = 0; k2 < 4; ++k2) {
            bf16x8 afr2[2];
#pragma unroll
            for (int rt = 0; rt < 2; ++rt) {
                int arow = wr * 32 + rt * 16 + (lane & 15);
                int k0 = k2 * 32 + (lane >> 4) * 8;
                u32 off = ((u32)(arow * 256 + k0 * 2)) ^ ((u32)(arow & 7) << 4);
                afr2[rt] = *(const bf16x8*)((const char*)sTp + off);
            }
#pragma unroll
            for (int ct = 0; ct < 4; ++ct) {
                size_t ctile = (size_t)(wc * 4 + ct);
                size_t ktile = (size_t)(12 + k2);
                bf16x8 bd = *(const bf16x8*)(wd + (ctile * 16 + ktile) * 512 + lane * 8);
#pragma unroll
                for (int rt = 0; rt < 2; ++rt)
                    accd[rt][ct] = MFMA16(afr2[rt], bd, accd[rt][ct]);
            }
        }
    }

    // ---- write dmid [64][256] n-slice as bf16
#pragma unroll
    for (int rt = 0; rt < 2; ++rt)
#pragma unroll
        for (int ct = 0; ct < 4; ++ct) {
            int rbase = m0 + wr * 32 + rt * 16 + (lane >> 4) * 4;
            int col = n * DSUB + wc * 64 + ct * 16 + (lane & 15);
#pragma unroll
            for (int q = 0; q < 4; ++q)
                dmid[(size_t)(rbase + q) * DMODEL + col] = f2bf(accd[rt][ct][q]);
        }
}

// -------------------------------------------------- final GEMM + residual
// grid: 1024 blocks -> (mb 128) x (nb 8); BM=128, BN=128; 512 thr, 8 waves.
// Locality decode: slot=bid&7, nb=(bid>>3)&7, mb=(bid>>6)*8+slot — the 8
// blocks sharing a dmid panel are temporally adjacent AND same-XCD.
// 2x32KB LDS double-buffer -> 2 blocks/CU. Per-chunk T14 split staging
// (transient regs: loads before compute, ds_writes after).
__global__ __launch_bounds__(512, 2) void k_final(const u16* __restrict__ dmid,
                                                  const u16* __restrict__ woP,   // [64][32][64][8]
                                                  const float* __restrict__ x,
                                                  float* __restrict__ out) {
    int bid = blockIdx.x;
    int slot = bid & 7;
    int nb = (bid >> 3) & 7;
    int mb = (bid >> 6) * 8 + slot;
    int m0 = mb * 128, n0 = nb * 128;
    int tid = threadIdx.x;
    int lane = tid & 63, wid = tid >> 6;
    int wr = wid >> 2, wc = wid & 3;

    __shared__ u16 sA[2][128 * 128];     // 2 x 32KB, swizzled

    const f32x4 zero = {0.f, 0.f, 0.f, 0.f};
    f32x4 acc[4][2];
#pragma unroll
    for (int a = 0; a < 4; ++a)
#pragma unroll
        for (int b = 0; b < 2; ++b) acc[a][b] = zero;

    const u16* dbase = dmid + (size_t)m0 * DMODEL;

    // prologue: stage chunk 0 -> sA[0]
#pragma unroll
    for (int it = 0; it < 4; ++it) {
        int e = (tid + it * 512) * 8;
        int r = e >> 7, c = e & 127;
        uint4 v = *(const uint4*)(dbase + (size_t)r * DMODEL + c);
        u32 off = ((u32)(r * 256 + c * 2)) ^ ((u32)(r & 7) << 4);
        *(uint4*)((char*)sA[0] + off) = v;
    }
    __syncthreads();

#pragma unroll
    for (int kc = 0; kc < 8; ++kc) {
        // issue next chunk's global loads (latency hides under compute)
        uint4 tmp[4];
        if (kc < 7) {
#pragma unroll
            for (int it = 0; it < 4; ++it) {
                int e = (tid + it * 512) * 8;
                int r = e >> 7, c = e & 127;
                tmp[it] = *(const uint4*)(dbase + (size_t)r * DMODEL + (kc + 1) * 128 + c);
            }
        }

        const u16* sAc = (const u16*)sA[kc & 1];
#pragma unroll
        for (int ks = 0; ks < 4; ++ks) {
            bf16x8 afr[4];
#pragma unroll
            for (int rt = 0; rt < 4; ++rt) {
                int arow = wr * 64 + rt * 16 + (lane & 15);
                int k0 = ks * 32 + (lane >> 4) * 8;
                u32 off = ((u32)(arow * 256 + k0 * 2)) ^ ((u32)(arow & 7) << 4);
                afr[rt] = *(const bf16x8*)((const char*)sAc + off);
            }
#pragma unroll
            for (int ct = 0; ct < 2; ++ct) {
                size_t ctile = (size_t)(nb * 8 + wc * 2 + ct);
                size_t ktile = (size_t)(kc * 4 + ks);
                bf16x8 wf = *(const bf16x8*)(woP + (ctile * 32 + ktile) * 512 + lane * 8);
#pragma unroll
                for (int rt = 0; rt < 4; ++rt)
                    acc[rt][ct] = MFMA16(afr[rt], wf, acc[rt][ct]);
            }
        }

        // write staged chunk into the free buffer, then barrier
        if (kc < 7) {
#pragma unroll
            for (int it = 0; it < 4; ++it) {
                int e = (tid + it * 512) * 8;
                int r = e >> 7, c = e & 127;
                u32 off = ((u32)(r * 256 + c * 2)) ^ ((u32)(r & 7) << 4);
                *(uint4*)((char*)sA[(kc + 1) & 1] + off) = tmp[it];
            }
        }
        __syncthreads();
    }

    // epilogue: residual add, fp32 store
#pragma unroll
    for (int rt = 0; rt < 4; ++rt)
#pragma unroll
        for (int ct = 0; ct < 2; ++ct) {
            int rbase = m0 + wr * 64 + rt * 16 + (lane >> 4) * 4;
            int col = n0 + wc * 32 + ct * 16 + (lane & 15);
#pragma unroll
            for (int q = 0; q < 4; ++q) {
                size_t o = (size_t)(rbase + q) * DMODEL + col;
                out[o] = acc[rt][ct][q] + x[o];
            }
        }
}

// ---------------------------------------------------------------- launcher
extern "C" void kernel_launch(void* const* d_in, const int* in_sizes, int n_in,
                              void* d_out, int out_size, void* d_ws, size_t ws_size,
                              hipStream_t stream) {
    const float* x  = (const float*)d_in[0];
    const float* nw = (const float*)d_in[1];
    const float* Wg = (const float*)d_in[2];
    const float* Wu = (const float*)d_in[3];
    const float* Wd = (const float*)d_in[4];
    const float* Wo = (const float*)d_in[5];
    float* out = (float*)d_out;

    char* ws = (char*)d_ws;
    const size_t MB = 1u << 20;
    u16* h    = (u16*)(ws);             // 32 MB
    u16* wgP  = (u16*)(ws + 32 * MB);   //  1 MB
    u16* wuP  = (u16*)(ws + 33 * MB);   //  1 MB
    u16* wdP  = (u16*)(ws + 34 * MB);   //  1 MB
    u16* woP  = (u16*)(ws + 35 * MB);   //  2 MB
    u16* dmid = (u16*)(ws + 37 * MB);   // 32 MB  (end: 69 MB)

    k_repack_all<<<1280, 256, 0, stream>>>(Wg, Wu, Wd, Wo, wgP, wuP, wdP, woP);
    k_norm_rope<<<NTOK, 256, 0, stream>>>(x, nw, h);
    k_swiglu<<<256 * NSUB, 512, 0, stream>>>(h, wgP, wuP, wdP, dmid);
    k_final<<<128 * 8, 512, 0, stream>>>(dmid, woP, x, out);
}